// Round 4
// baseline (140.217 us; speedup 1.0000x reference)
//
#include <hip/hip_runtime.h>
#include <math.h>

#define BB 64
#define TT 2048
#define DD 512
#define UU 10
#define S_CHUNKS 32
#define CHUNK_T (TT / S_CHUNKS)   // 64 t per block, 16 per wave, 4 batches of 4
#define NB (CHUNK_T / 16)         // 4 batches per wave

__device__ __forceinline__ float fast_tanh(float x) {
    // tanh(x) = 1 - 2/(1+e^{2x}); robust at +-inf
    return 1.0f - 2.0f / (1.0f + __expf(2.0f * x));
}

// Scores are bounded: |s| <= |b_s| + sum|W_s| (tanh in [-1,1]) ~ 4, so exp(s)
// never overflows and softmax needs NO max subtraction: p = exp(s), w = p/sum(p).
//
// Register budget is the occupancy lever: u-outer projection keeps only 4 live
// dot temps (vs acc[4][10]); wv[8][10]=80 + e[4][8]=32 + misc ~ <=170 VGPR
// -> 3 waves/SIMD (launch_bounds pins the allocator).
__global__ __launch_bounds__(256, 3) void attn_pass1(
    const float* __restrict__ Eo, const float* __restrict__ H,
    const float* __restrict__ W_eo, const float* __restrict__ b_eo,
    const float* __restrict__ W_h, const float* __restrict__ b_h,
    const float* __restrict__ W_s, const float* __restrict__ b_s,
    float* __restrict__ pexp, float* __restrict__ pc)
{
    const int b     = blockIdx.y;
    const int chunk = blockIdx.x;
    const int tid   = threadIdx.x;
    const int wave  = tid >> 6;
    const int lane  = tid & 63;

    // ---- hb[u] = (H[b]*W_h)[u] + b_h[u] + b_eo[u]  (once per wave)
    float hacc[UU];
    #pragma unroll
    for (int u = 0; u < UU; ++u) hacc[u] = 0.f;
    const float* Hb = H + (size_t)b * DD;
    #pragma unroll
    for (int k = 0; k < DD / 64; ++k) {
        float hv = Hb[k * 64 + lane];
        const float* wr = W_h + (size_t)(k * 64 + lane) * UU;
        #pragma unroll
        for (int u = 0; u < UU; ++u) hacc[u] += hv * wr[u];
    }
    #pragma unroll
    for (int off = 1; off < 64; off <<= 1) {
        #pragma unroll
        for (int u = 0; u < UU; ++u) hacc[u] += __shfl_xor(hacc[u], off, 64);
    }
    float hb[UU];
    #pragma unroll
    for (int u = 0; u < UU; ++u) hb[u] = hacc[u] + b_h[u] + b_eo[u];

    float wsv[UU];
    #pragma unroll
    for (int u = 0; u < UU; ++u) wsv[u] = W_s[u];   // uniform -> scalar loads
    const float bs = b_s[0];

    // ---- per-lane W_eo slice (80 VGPRs, loaded once, reused for all t)
    float wv[8][UU];
    #pragma unroll
    for (int k = 0; k < 2; ++k) {
        #pragma unroll
        for (int j = 0; j < 4; ++j) {
            const float* wr = W_eo + (size_t)(k * 256 + 4 * lane + j) * UU;
            #pragma unroll
            for (int u = 0; u < UU; ++u) wv[k * 4 + j][u] = wr[u];
        }
    }

    float l = 0.f;
    float c[8];
    #pragma unroll
    for (int j = 0; j < 8; ++j) c[j] = 0.f;

    const int  t0w  = chunk * CHUNK_T + wave * (CHUNK_T / 4);
    const bool lo32 = (lane & 32) == 0;
    const bool lo16 = (lane & 16) == 0;
    const float* rowbase = Eo + (size_t)b * TT * DD + 4 * lane;

    #pragma unroll
    for (int i = 0; i < NB; ++i) {
        const int tb = t0w + i * 4;

        // load e for 4 t's (8 independent float4 loads)
        float e[4][8];
        #pragma unroll
        for (int tt = 0; tt < 4; ++tt) {
            const float* row = rowbase + (size_t)(tb + tt) * DD;
            float4 e0 = *(const float4*)(row);
            float4 e1 = *(const float4*)(row + 256);
            e[tt][0] = e0.x; e[tt][1] = e0.y; e[tt][2] = e0.z; e[tt][3] = e0.w;
            e[tt][4] = e1.x; e[tt][5] = e1.y; e[tt][6] = e1.z; e[tt][7] = e1.w;
        }

        // u-outer: per u, 4 partial dots + immediate fold-reduce; only 4 live
        // temps instead of acc[4][10]. Unrolled -> scheduler interleaves the
        // independent u-chains to hide shfl latency.
        float s = bs;
        #pragma unroll
        for (int u = 0; u < UU; ++u) {
            float a0 = 0.f, a1 = 0.f, a2 = 0.f, a3 = 0.f;
            #pragma unroll
            for (int j = 0; j < 8; ++j) {
                const float w = wv[j][u];
                a0 += e[0][j] * w;
                a1 += e[1][j] * w;
                a2 += e[2][j] * w;
                a3 += e[3][j] * w;
            }
            float y0 = lo32 ? a0 : a2;
            float o0 = lo32 ? a2 : a0;
            y0 += __shfl_xor(o0, 32, 64);
            float y1 = lo32 ? a1 : a3;
            float o1 = lo32 ? a3 : a1;
            y1 += __shfl_xor(o1, 32, 64);
            float z  = lo16 ? y0 : y1;
            float oz = lo16 ? y1 : y0;
            z += __shfl_xor(oz, 16, 64);
            z += __shfl_xor(z, 8, 64);
            z += __shfl_xor(z, 4, 64);
            z += __shfl_xor(z, 2, 64);
            z += __shfl_xor(z, 1, 64);
            // group g = lane>>4 holds full proj of t = tb + g for this u
            s += wsv[u] * fast_tanh(z + hb[u]);
        }
        float p = __expf(s);

        if ((lane & 15) == 0) pexp[(size_t)b * TT + tb + (lane >> 4)] = p;

        // broadcast the 4 p's; accumulate unnormalized context (no rescale)
        float p0 = __shfl(p, 0, 64);
        float p1 = __shfl(p, 16, 64);
        float p2 = __shfl(p, 32, 64);
        float p3 = __shfl(p, 48, 64);
        l += (p0 + p1) + (p2 + p3);
        #pragma unroll
        for (int j = 0; j < 8; ++j)
            c[j] += p0 * e[0][j] + p1 * e[1][j] + p2 * e[2][j] + p3 * e[3][j];
    }

    // ---- combine the block's 4 waves in LDS (l recomputed from pexp in epilogue)
    __shared__ float sc[4][DD];
    #pragma unroll
    for (int k = 0; k < 2; ++k) {
        #pragma unroll
        for (int j = 0; j < 4; ++j)
            sc[wave][k * 256 + 4 * lane + j] = c[k * 4 + j];
    }
    __syncthreads();

    const int pidx = b * S_CHUNKS + chunk;
    for (int d = tid; d < DD; d += 256) {
        pc[(size_t)pidx * DD + d] = (sc[0][d] + sc[1][d]) + (sc[2][d] + sc[3][d]);
    }
}

// Fused epilogue: per batch b -- l = sum(pexp), context = sum(pc)/l,
// weight = pexp/l. One block per b.
__global__ __launch_bounds__(256) void attn_epilogue(
    const float* __restrict__ pexp, const float* __restrict__ pc,
    float* __restrict__ ctx_out, float* __restrict__ wout)
{
    const int b = blockIdx.x;
    const int tid = threadIdx.x;
    const int wave = tid >> 6;

    // l = sum over 2048 pexp values
    float s = 0.f;
    #pragma unroll
    for (int k = 0; k < TT / 256; ++k) s += pexp[(size_t)b * TT + k * 256 + tid];
    #pragma unroll
    for (int off = 1; off < 64; off <<= 1) s += __shfl_xor(s, off, 64);

    __shared__ float sl[4];
    if ((tid & 63) == 0) sl[wave] = s;
    __syncthreads();
    const float l = (sl[0] + sl[1]) + (sl[2] + sl[3]);
    const float inv = 1.0f / l;

    for (int d = tid; d < DD; d += 256) {
        float v = 0.f;
        #pragma unroll
        for (int sss = 0; sss < S_CHUNKS; ++sss)
            v += pc[((size_t)(b * S_CHUNKS + sss)) * DD + d];
        ctx_out[(size_t)b * DD + d] = v * inv;
    }
    for (int t = tid; t < TT; t += 256)
        wout[(size_t)b * TT + t] = pexp[(size_t)b * TT + t] * inv;
}

extern "C" void kernel_launch(void* const* d_in, const int* in_sizes, int n_in,
                              void* d_out, int out_size, void* d_ws, size_t ws_size,
                              hipStream_t stream) {
    const float* Eo   = (const float*)d_in[0];
    const float* H    = (const float*)d_in[1];
    const float* W_eo = (const float*)d_in[2];
    const float* b_eo = (const float*)d_in[3];
    const float* W_h  = (const float*)d_in[4];
    const float* b_h  = (const float*)d_in[5];
    const float* W_s  = (const float*)d_in[6];
    const float* b_s  = (const float*)d_in[7];

    // ws layout (floats): pexp[B*T] | pc[B*S*D]
    float* pexp = (float*)d_ws;
    float* pc   = pexp + (size_t)BB * TT;

    float* out_ctx = (float*)d_out;                 // [B, D]
    float* out_w   = out_ctx + (size_t)BB * DD;     // [B, T, 1]

    dim3 gridA(S_CHUNKS, BB);
    attn_pass1<<<gridA, 256, 0, stream>>>(Eo, H, W_eo, b_eo, W_h, b_h, W_s, b_s,
                                          pexp, pc);
    attn_epilogue<<<BB, 256, 0, stream>>>(pexp, pc, out_ctx, out_w);
}

// Round 5
// 65.562 us; speedup vs baseline: 2.1387x; 2.1387x over previous
//
#include <hip/hip_runtime.h>
#include <math.h>

#define BB 64
#define TT 2048
#define DD 512
#define UU 10
#define S_CHUNKS 16
#define CHUNK_T (TT / S_CHUNKS)   // 128 t per block, 32 per wave, 8 batches of 4
#define NB (CHUNK_T / 16)         // 8 batches per wave

__device__ __forceinline__ float fast_tanh(float x) {
    // tanh(x) = 1 - 2/(1+e^{2x}); robust at +-inf
    return 1.0f - 2.0f / (1.0f + __expf(2.0f * x));
}

// DPP row_shr:K accumulate (VALU pipe, not DS): lane i reads lane i-K within
// its 16-lane row; out-of-row reads return 0 (bound_ctrl). Chaining K=1,2,4,8
// leaves the full row sum in lane 15 of each row.
template<int K>
__device__ __forceinline__ float dpp_shr(float x) {
    int xi = __builtin_bit_cast(int, x);
    int r  = __builtin_amdgcn_update_dpp(0, xi, 0x110 | K, 0xF, 0xF, true);
    return __builtin_bit_cast(float, r);
}

__device__ __forceinline__ float read_lane_f(float v, int lane) {
    return __builtin_bit_cast(float,
        __builtin_amdgcn_readlane(__builtin_bit_cast(int, v), lane));
}

// Scores are bounded: |s| <= |b_s| + sum|W_s| (tanh in [-1,1]) ~ 4, so exp(s)
// never overflows and softmax needs NO max subtraction: p = exp(s), w = p/sum(p).
__global__ __launch_bounds__(256) void attn_pass1(
    const float* __restrict__ Eo, const float* __restrict__ H,
    const float* __restrict__ W_eo, const float* __restrict__ b_eo,
    const float* __restrict__ W_h, const float* __restrict__ b_h,
    const float* __restrict__ W_s, const float* __restrict__ b_s,
    float* __restrict__ pexp, float* __restrict__ pc)
{
    const int b     = blockIdx.y;
    const int chunk = blockIdx.x;
    const int tid   = threadIdx.x;
    const int wave  = tid >> 6;
    const int lane  = tid & 63;

    // ---- hb[u] = (H[b]*W_h)[u] + b_h[u] + b_eo[u]  (once per wave)
    float hacc[UU];
    #pragma unroll
    for (int u = 0; u < UU; ++u) hacc[u] = 0.f;
    const float* Hb = H + (size_t)b * DD;
    #pragma unroll
    for (int k = 0; k < DD / 64; ++k) {
        float hv = Hb[k * 64 + lane];
        const float* wr = W_h + (size_t)(k * 64 + lane) * UU;
        #pragma unroll
        for (int u = 0; u < UU; ++u) hacc[u] += hv * wr[u];
    }
    #pragma unroll
    for (int off = 1; off < 64; off <<= 1) {
        #pragma unroll
        for (int u = 0; u < UU; ++u) hacc[u] += __shfl_xor(hacc[u], off, 64);
    }
    float hb[UU];
    #pragma unroll
    for (int u = 0; u < UU; ++u) hb[u] = hacc[u] + b_h[u] + b_eo[u];

    float wsv[UU];
    #pragma unroll
    for (int u = 0; u < UU; ++u) wsv[u] = W_s[u];   // uniform -> scalar loads
    const float bs = b_s[0];

    // ---- per-lane W_eo slice (80 VGPRs, loaded once, reused for all t)
    float wv[8][UU];
    #pragma unroll
    for (int k = 0; k < 2; ++k) {
        #pragma unroll
        for (int j = 0; j < 4; ++j) {
            const float* wr = W_eo + (size_t)(k * 256 + 4 * lane + j) * UU;
            #pragma unroll
            for (int u = 0; u < UU; ++u) wv[k * 4 + j][u] = wr[u];
        }
    }

    float l = 0.f;
    float c[8];
    #pragma unroll
    for (int j = 0; j < 8; ++j) c[j] = 0.f;

    const int  t0w  = chunk * CHUNK_T + wave * (CHUNK_T / 4);
    const bool lo32 = (lane & 32) == 0;
    const bool lo16 = (lane & 16) == 0;
    const float* rowbase = Eo + (size_t)b * TT * DD + 4 * lane;

    for (int i = 0; i < NB; ++i) {      // 8 batches of 4 t
        const int tb = t0w + i * 4;

        // load e for 4 t's up front (8 independent float4 loads)
        float e[4][8];
        #pragma unroll
        for (int tt = 0; tt < 4; ++tt) {
            const float* row = rowbase + (size_t)(tb + tt) * DD;
            float4 e0 = *(const float4*)(row);
            float4 e1 = *(const float4*)(row + 256);
            e[tt][0] = e0.x; e[tt][1] = e0.y; e[tt][2] = e0.z; e[tt][3] = e0.w;
            e[tt][4] = e1.x; e[tt][5] = e1.y; e[tt][6] = e1.z; e[tt][7] = e1.w;
        }

        // per-lane partial projections for 4 t's
        float acc[4][UU];
        #pragma unroll
        for (int tt = 0; tt < 4; ++tt) {
            #pragma unroll
            for (int u = 0; u < UU; ++u) acc[tt][u] = 0.f;
            #pragma unroll
            for (int j = 0; j < 8; ++j) {
                #pragma unroll
                for (int u = 0; u < UU; ++u) acc[tt][u] += e[tt][j] * wv[j][u];
            }
        }

        // fold-reduce: select+xor32, select+xor16 (DS; proven), then 4 DPP
        // row_shr levels (VALU). Row sum for t_g lands in lane 16g+15.
        float s = bs;
        #pragma unroll
        for (int u = 0; u < UU; ++u) {
            float y0 = lo32 ? acc[0][u] : acc[2][u];
            float o0 = lo32 ? acc[2][u] : acc[0][u];
            y0 += __shfl_xor(o0, 32, 64);
            float y1 = lo32 ? acc[1][u] : acc[3][u];
            float o1 = lo32 ? acc[3][u] : acc[1][u];
            y1 += __shfl_xor(o1, 32, 64);
            float z  = lo16 ? y0 : y1;
            float oz = lo16 ? y1 : y0;
            z += __shfl_xor(oz, 16, 64);
            z += dpp_shr<1>(z);
            z += dpp_shr<2>(z);
            z += dpp_shr<4>(z);
            z += dpp_shr<8>(z);
            // only lanes 15,31,47,63 hold the true sum; tanh keeps the rest
            // bounded so s never overflows anywhere.
            s += wsv[u] * fast_tanh(z + hb[u]);
        }
        float p = __expf(s);

        if ((lane & 15) == 15) pexp[(size_t)b * TT + tb + (lane >> 4)] = p;

        // broadcast the 4 valid p's via readlane (SGPR, no DS traffic)
        float p0 = read_lane_f(p, 15);
        float p1 = read_lane_f(p, 31);
        float p2 = read_lane_f(p, 47);
        float p3 = read_lane_f(p, 63);
        l += (p0 + p1) + (p2 + p3);
        #pragma unroll
        for (int j = 0; j < 8; ++j)
            c[j] += p0 * e[0][j] + p1 * e[1][j] + p2 * e[2][j] + p3 * e[3][j];
    }

    // ---- combine the block's 4 waves in LDS (l recomputed from pexp in epilogue)
    __shared__ float sc[4][DD];
    #pragma unroll
    for (int k = 0; k < 2; ++k) {
        #pragma unroll
        for (int j = 0; j < 4; ++j)
            sc[wave][k * 256 + 4 * lane + j] = c[k * 4 + j];
    }
    __syncthreads();

    const int pidx = b * S_CHUNKS + chunk;
    for (int d = tid; d < DD; d += 256) {
        pc[(size_t)pidx * DD + d] = (sc[0][d] + sc[1][d]) + (sc[2][d] + sc[3][d]);
    }
}

// Fused epilogue: per batch b -- l = sum(pexp), context = sum(pc)/l,
// weight = pexp/l. One block per b.
__global__ __launch_bounds__(256) void attn_epilogue(
    const float* __restrict__ pexp, const float* __restrict__ pc,
    float* __restrict__ ctx_out, float* __restrict__ wout)
{
    const int b = blockIdx.x;
    const int tid = threadIdx.x;
    const int wave = tid >> 6;

    // l = sum over 2048 pexp values
    float s = 0.f;
    #pragma unroll
    for (int k = 0; k < TT / 256; ++k) s += pexp[(size_t)b * TT + k * 256 + tid];
    #pragma unroll
    for (int off = 1; off < 64; off <<= 1) s += __shfl_xor(s, off, 64);

    __shared__ float sl[4];
    if ((tid & 63) == 0) sl[wave] = s;
    __syncthreads();
    const float l = (sl[0] + sl[1]) + (sl[2] + sl[3]);
    const float inv = 1.0f / l;

    for (int d = tid; d < DD; d += 256) {
        float v = 0.f;
        #pragma unroll
        for (int sss = 0; sss < S_CHUNKS; ++sss)
            v += pc[((size_t)(b * S_CHUNKS + sss)) * DD + d];
        ctx_out[(size_t)b * DD + d] = v * inv;
    }
    for (int t = tid; t < TT; t += 256)
        wout[(size_t)b * TT + t] = pexp[(size_t)b * TT + t] * inv;
}

extern "C" void kernel_launch(void* const* d_in, const int* in_sizes, int n_in,
                              void* d_out, int out_size, void* d_ws, size_t ws_size,
                              hipStream_t stream) {
    const float* Eo   = (const float*)d_in[0];
    const float* H    = (const float*)d_in[1];
    const float* W_eo = (const float*)d_in[2];
    const float* b_eo = (const float*)d_in[3];
    const float* W_h  = (const float*)d_in[4];
    const float* b_h  = (const float*)d_in[5];
    const float* W_s  = (const float*)d_in[6];
    const float* b_s  = (const float*)d_in[7];

    // ws layout (floats): pexp[B*T] | pc[B*S*D]
    float* pexp = (float*)d_ws;
    float* pc   = pexp + (size_t)BB * TT;

    float* out_ctx = (float*)d_out;                 // [B, D]
    float* out_w   = out_ctx + (size_t)BB * DD;     // [B, T, 1]

    dim3 gridA(S_CHUNKS, BB);
    attn_pass1<<<gridA, 256, 0, stream>>>(Eo, H, W_eo, b_eo, W_h, b_h, W_s, b_s,
                                          pexp, pc);
    attn_epilogue<<<BB, 256, 0, stream>>>(pexp, pc, out_ctx, out_w);
}